// Round 21
// baseline (110.605 us; speedup 1.0000x reference)
//
#include <hip/hip_runtime.h>
#include <hip/hip_fp16.h>

// RNNT Joint: logits[b,t,u,c] = relu(f[b,t,:] + g[b,u,:]) . out_w[c,:] + out_b[c]
// f = enc_out @ enc_w^T + enc_b    [8,512,320]
// g = pred_out @ pred_w^T + pred_b [8,128,320]
// Sizes: B=8 T=512 U=128 E=768 P=320 H=320 C=34

typedef _Float16 f16x8 __attribute__((ext_vector_type(8)));
typedef _Float16 f16x4 __attribute__((ext_vector_type(4)));
typedef __fp16   fp16x2 __attribute__((ext_vector_type(2)));
typedef float    f32x4 __attribute__((ext_vector_type(4)));
typedef int      i32x4 __attribute__((ext_vector_type(4)));

#define B_ 8
#define T_ 512
#define U_ 128
#define H_ 320
#define C_ 34

__device__ inline f16x8 pack8(f32x4 a, f32x4 b) {
    union { fp16x2 h[4]; f16x8 v; } u;
    u.h[0] = __builtin_amdgcn_cvt_pkrtz(a[0], a[1]);
    u.h[1] = __builtin_amdgcn_cvt_pkrtz(a[2], a[3]);
    u.h[2] = __builtin_amdgcn_cvt_pkrtz(b[0], b[1]);
    u.h[3] = __builtin_amdgcn_cvt_pkrtz(b[2], b[3]);
    return u.v;
}

__device__ inline f16x4 pack4(f32x4 a) {
    union { fp16x2 h[2]; f16x4 v; } u;
    u.h[0] = __builtin_amdgcn_cvt_pkrtz(a[0], a[1]);
    u.h[1] = __builtin_amdgcn_cvt_pkrtz(a[2], a[3]);
    return u.v;
}

// ---------------------------------------------------------------------------
// Fused projection GEMMs (proven R7): Out[M][320] = A[M][K]*W[320][K]^T + bias.
// ---------------------------------------------------------------------------
__global__ __launch_bounds__(512, 4)
void proj_fused(const float* __restrict__ enc_out, const float* __restrict__ enc_w,
                const float* __restrict__ enc_b, const float* __restrict__ pred_out,
                const float* __restrict__ pred_w, const float* __restrict__ pred_b,
                _Float16* __restrict__ F, _Float16* __restrict__ G) {
    __shared__ _Float16 As[2][64 * 40];
    __shared__ _Float16 Ws[2][64 * 40];

    int blk = blockIdx.x;
    const float *A, *W, *bias;
    _Float16* Out;
    int K, mt, nt;
    if (blk < 320) {
        A = enc_out; W = enc_w; bias = enc_b; Out = F; K = 768;
        mt = blk & 63; nt = blk >> 6;
    } else {
        blk -= 320;
        A = pred_out; W = pred_w; bias = pred_b; Out = G; K = 320;
        mt = blk & 15; nt = blk >> 4;
    }
    const int bm = mt * 64;
    const int bn = nt * 64;

    const int tid = threadIdx.x;
    const int l   = tid & 63;
    const int w   = tid >> 6;          // 0..7
    const int wm  = (w >> 2) * 32;     // 0,32
    const int wn  = (w & 3) * 16;      // 0,16,32,48
    const int q   = l >> 4;            // 0..3 (k-slice group)
    const int r16 = l & 15;

    const int srow = tid >> 3;         // 0..63
    const int scol = (tid & 7) * 4;    // float col 0,4,...,28

    f32x4 acc[2] = {};

    const float* arow = A + (size_t)(bm + srow) * K + scol;
    const float* wrow = W + (size_t)(bn + srow) * K + scol;

    // 2-deep prologue: K-steps 0 and 32 in flight
    f32x4 aA = *(const f32x4*)(arow);
    f32x4 wA = *(const f32x4*)(wrow);
    f32x4 aB = *(const f32x4*)(arow + 32);
    f32x4 wB = *(const f32x4*)(wrow + 32);

    for (int k0 = 0; k0 < K; k0 += 64) {
        // ---- phase A (buffer 0, K-step k0) ----
        *(f16x4*)&As[0][srow * 40 + scol] = pack4(aA);
        *(f16x4*)&Ws[0][srow * 40 + scol] = pack4(wA);
        if (k0 + 64 < K) {
            aA = *(const f32x4*)(arow + k0 + 64);
            wA = *(const f32x4*)(wrow + k0 + 64);
        }
        __syncthreads();
        {
            f16x8 af0 = *(const f16x8*)&As[0][(wm + r16) * 40 + q * 8];
            f16x8 af1 = *(const f16x8*)&As[0][(wm + 16 + r16) * 40 + q * 8];
            f16x8 bf  = *(const f16x8*)&Ws[0][(wn + r16) * 40 + q * 8];
            acc[0] = __builtin_amdgcn_mfma_f32_16x16x32_f16(af0, bf, acc[0], 0, 0, 0);
            acc[1] = __builtin_amdgcn_mfma_f32_16x16x32_f16(af1, bf, acc[1], 0, 0, 0);
        }
        // ---- phase B (buffer 1, K-step k0+32) ----
        *(f16x4*)&As[1][srow * 40 + scol] = pack4(aB);
        *(f16x4*)&Ws[1][srow * 40 + scol] = pack4(wB);
        if (k0 + 96 < K) {
            aB = *(const f32x4*)(arow + k0 + 96);
            wB = *(const f32x4*)(wrow + k0 + 96);
        }
        __syncthreads();
        {
            f16x8 af0 = *(const f16x8*)&As[1][(wm + r16) * 40 + q * 8];
            f16x8 af1 = *(const f16x8*)&As[1][(wm + 16 + r16) * 40 + q * 8];
            f16x8 bf  = *(const f16x8*)&Ws[1][(wn + r16) * 40 + q * 8];
            acc[0] = __builtin_amdgcn_mfma_f32_16x16x32_f16(af0, bf, acc[0], 0, 0, 0);
            acc[1] = __builtin_amdgcn_mfma_f32_16x16x32_f16(af1, bf, acc[1], 0, 0, 0);
        }
    }

    // Epilogue: C/D layout col = l&15 (n), row = (l>>4)*4 + rr (m)  [m89]
    {
        int col  = bn + wn + r16;
        float bv = bias[col];
#pragma unroll
        for (int mrep = 0; mrep < 2; ++mrep) {
#pragma unroll
            for (int rr = 0; rr < 4; ++rr) {
                int row = bm + wm + mrep * 16 + q * 4 + rr;
                Out[(size_t)row * H_ + col] = (_Float16)(acc[mrep][rr] + bv);
            }
        }
    }
}

// ---------------------------------------------------------------------------
// Joint kernel v15: the CLEAN 3-blocks/CU test (R13/R15 were spill-confounded).
// LDS: ow 34 rows (21760) + flds (20480) + slabs (8704) = 50944 B -> 3
// blocks/CU = 12 waves/CU (3 waves/SIMD, +50% TLP vs R20). NO overlay ->
// compiler free to sink bfr reads (costs ~0.5us, proven R20) -> VGPR ~100
// fits the (256,3) cap ~170 -> NO spill. NT dumps keep the write stream out
// of L2 -> 768 concurrent blocks' read-set (~15MB F + shared out_w) L2-fits.
// ---------------------------------------------------------------------------
__global__ __launch_bounds__(256, 3)
void joint_kernel(const _Float16* __restrict__ F, const _Float16* __restrict__ G,
                  const float* __restrict__ out_w, const float* __restrict__ out_b,
                  float* __restrict__ out) {
    __shared__ _Float16 owlds[34 * 320];  // 21760 B; row stride 640 B, XOR-swizzled
    __shared__ _Float16 flds[32 * 320];   // 20480 B; linear
    __shared__ float    olds[4][544];     //  8704 B; per-wave 2176 B output slab

    const int tid = threadIdx.x;
    const int l   = tid & 63;
    const int w   = tid >> 6;
    const int q   = l >> 4;    // 0..3
    const int r16 = l & 15;
    const int tc  = blockIdx.x;  // 0..15 (t-chunk of 32)
    const int ut  = blockIdx.y;  // 0..7 (u-tile of 16)
    const int b   = blockIdx.z;  // 0..7
    const int u0  = ut * 16;

    char* ow = (char*)owlds;

    // stage out_w [34][320] fp32 -> fp16 swizzled LDS [34][320]
    for (int i = tid; i < 34 * 40; i += 256) {   // 1360 chunks of 8 f16
        int n  = i / 40;
        int c8 = (i - n * 40) * 8;               // f16 column
        f32x4 x0 = *(const f32x4*)(out_w + n * H_ + c8);
        f32x4 x1 = *(const f32x4*)(out_w + n * H_ + c8 + 4);
        *(f16x8*)(ow + n * 640 + ((c8 * 2) ^ ((n & 7) << 4))) = pack8(x0, x1);
    }

    // stage F chunk [32][320] f16 -> LDS, fully coalesced (1280 x 16B)
    {
        const _Float16* fsrc = F + ((size_t)b * T_ + tc * 32) * H_;
        for (int i = tid; i < 1280; i += 256)
            *(i32x4*)&flds[i * 8] = *(const i32x4*)(fsrc + i * 8);
    }

    // g fragments: per-lane row u0+r16, loop-invariant over t (A-operand m=u)
    f16x8 gfr[10];
    {
        const _Float16* grow = G + ((size_t)b * U_ + u0 + r16) * H_;
#pragma unroll
        for (int s = 0; s < 10; ++s)
            gfr[s] = *(const f16x8*)(grow + s * 32 + q * 8);
    }

    float ob[3];
#pragma unroll
    for (int nt = 0; nt < 3; ++nt) {
        int n = nt * 16 + r16;
        ob[nt] = (n < C_) ? out_b[n] : 0.f;
    }

    __syncthreads();

    // B-fragments (n=class) from swizzled LDS (conflict-free b128).
    // nt=2: only classes 32,33 exist -> r16<2 predicate (no zero-padded rows).
    f16x8 bfr[3][10];
#pragma unroll
    for (int nt = 0; nt < 2; ++nt) {
        int n = nt * 16 + r16;
#pragma unroll
        for (int s = 0; s < 10; ++s)
            bfr[nt][s] = *(const f16x8*)(ow + n * 640 + ((s * 64 + q * 16) ^ ((n & 7) << 4)));
    }
#pragma unroll
    for (int s = 0; s < 10; ++s) {
        f16x8 v = {};
        if (r16 < 2) {
            int n = 32 + r16;
            v = *(const f16x8*)(ow + n * 640 + ((s * 64 + q * 16) ^ ((n & 7) << 4)));
        }
        bfr[2][s] = v;
    }

    float* slab = &olds[w][0];
    const f32x4* src = (const f32x4*)slab;
    const int tloc0 = w * 8;             // local t row within chunk

#pragma unroll
    for (int it = 0; it < 4; ++it) {
        const int tl0 = tloc0 + it * 2;
        const _Float16* fr0 = &flds[tl0 * 320];
        const _Float16* fr1 = &flds[(tl0 + 1) * 320];

        f32x4 a00 = {}, a01 = {}, a02 = {};
        f32x4 a10 = {}, a11 = {}, a12 = {};
        __builtin_amdgcn_s_setprio(1);
#pragma unroll
        for (int s = 0; s < 10; ++s) {
            const f16x8 fz = {};
            f16x8 fv0 = *(const f16x8*)(fr0 + s * 32 + q * 8);
            f16x8 fv1 = *(const f16x8*)(fr1 + s * 32 + q * 8);
            f16x8 jv0 = __builtin_elementwise_max(fv0 + gfr[s], fz);
            f16x8 jv1 = __builtin_elementwise_max(fv1 + gfr[s], fz);
            a00 = __builtin_amdgcn_mfma_f32_16x16x32_f16(jv0, bfr[0][s], a00, 0, 0, 0);
            a10 = __builtin_amdgcn_mfma_f32_16x16x32_f16(jv1, bfr[0][s], a10, 0, 0, 0);
            a01 = __builtin_amdgcn_mfma_f32_16x16x32_f16(jv0, bfr[1][s], a01, 0, 0, 0);
            a11 = __builtin_amdgcn_mfma_f32_16x16x32_f16(jv1, bfr[1][s], a11, 0, 0, 0);
            a02 = __builtin_amdgcn_mfma_f32_16x16x32_f16(jv0, bfr[2][s], a02, 0, 0, 0);
            a12 = __builtin_amdgcn_mfma_f32_16x16x32_f16(jv1, bfr[2][s], a12, 0, 0, 0);
        }
        __builtin_amdgcn_s_setprio(0);

        const int t0 = tc * 32 + tl0;
        float* ob0 = out + (((size_t)b * T_ + t0) * U_ + u0) * C_;  // 64B-aligned
        float* ob1 = ob0 + (size_t)U_ * C_;

        // ---- t0: scatter slab, dump NT full-line ----
#pragma unroll
        for (int rr = 0; rr < 4; ++rr) {
            const int m = q * 4 + rr;
            slab[m * 34 + r16]      = a00[rr] + ob[0];
            slab[m * 34 + 16 + r16] = a01[rr] + ob[1];
            if (r16 < 2)
                slab[m * 34 + 32 + r16] = a02[rr] + ob[2];
        }
        {
            f32x4 v0 = src[l];
            f32x4 v1 = src[64 + l];
            __builtin_nontemporal_store(v0, (f32x4*)(ob0 + l * 4));
            __builtin_nontemporal_store(v1, (f32x4*)(ob0 + 256 + l * 4));
            if (l < 8) {
                f32x4 v2 = src[128 + l];
                __builtin_nontemporal_store(v2, (f32x4*)(ob0 + 512 + l * 4));
            }
        }

        // ---- t1: reuse slab (same-wave LDS ops retire in order), dump NT ----
#pragma unroll
        for (int rr = 0; rr < 4; ++rr) {
            const int m = q * 4 + rr;
            slab[m * 34 + r16]      = a10[rr] + ob[0];
            slab[m * 34 + 16 + r16] = a11[rr] + ob[1];
            if (r16 < 2)
                slab[m * 34 + 32 + r16] = a12[rr] + ob[2];
        }
        {
            f32x4 v0 = src[l];
            f32x4 v1 = src[64 + l];
            __builtin_nontemporal_store(v0, (f32x4*)(ob1 + l * 4));
            __builtin_nontemporal_store(v1, (f32x4*)(ob1 + 256 + l * 4));
            if (l < 8) {
                f32x4 v2 = src[128 + l];
                __builtin_nontemporal_store(v2, (f32x4*)(ob1 + 512 + l * 4));
            }
        }
    }
}

// ---------------------------------------------------------------------------
extern "C" void kernel_launch(void* const* d_in, const int* in_sizes, int n_in,
                              void* d_out, int out_size, void* d_ws, size_t ws_size,
                              hipStream_t stream) {
    const float* enc_out  = (const float*)d_in[0];
    const float* pred_out = (const float*)d_in[1];
    const float* enc_w    = (const float*)d_in[2];
    const float* enc_b    = (const float*)d_in[3];
    const float* pred_w   = (const float*)d_in[4];
    const float* pred_b   = (const float*)d_in[5];
    const float* out_w    = (const float*)d_in[6];
    const float* out_b    = (const float*)d_in[7];
    float* out = (float*)d_out;

    char* ws = (char*)d_ws;
    _Float16* F = (_Float16*)ws;                            // 4096*320 fp16
    _Float16* G = (_Float16*)(ws + (size_t)4096 * 320 * 2); // 1024*320 fp16

    proj_fused<<<400, 512, 0, stream>>>(enc_out, enc_w, enc_b,
                                        pred_out, pred_w, pred_b, F, G);
    joint_kernel<<<dim3(16, 8, 8), 256, 0, stream>>>(F, G, out_w, out_b, out);
}

// Round 22
// 42.552 us; speedup vs baseline: 2.5993x; 2.5993x over previous
//
#include <hip/hip_runtime.h>
#include <hip/hip_fp16.h>

// RNNT Joint: logits[b,t,u,c] = relu(f[b,t,:] + g[b,u,:]) . out_w[c,:] + out_b[c]
// f = enc_out @ enc_w^T + enc_b    [8,512,320]
// g = pred_out @ pred_w^T + pred_b [8,128,320]
// Sizes: B=8 T=512 U=128 E=768 P=320 H=320 C=34

typedef _Float16 f16x8 __attribute__((ext_vector_type(8)));
typedef _Float16 f16x4 __attribute__((ext_vector_type(4)));
typedef __fp16   fp16x2 __attribute__((ext_vector_type(2)));
typedef float    f32x4 __attribute__((ext_vector_type(4)));
typedef int      i32x4 __attribute__((ext_vector_type(4)));

#define B_ 8
#define T_ 512
#define U_ 128
#define H_ 320
#define C_ 34

__device__ inline f16x8 pack8(f32x4 a, f32x4 b) {
    union { fp16x2 h[4]; f16x8 v; } u;
    u.h[0] = __builtin_amdgcn_cvt_pkrtz(a[0], a[1]);
    u.h[1] = __builtin_amdgcn_cvt_pkrtz(a[2], a[3]);
    u.h[2] = __builtin_amdgcn_cvt_pkrtz(b[0], b[1]);
    u.h[3] = __builtin_amdgcn_cvt_pkrtz(b[2], b[3]);
    return u.v;
}

__device__ inline f16x4 pack4(f32x4 a) {
    union { fp16x2 h[2]; f16x4 v; } u;
    u.h[0] = __builtin_amdgcn_cvt_pkrtz(a[0], a[1]);
    u.h[1] = __builtin_amdgcn_cvt_pkrtz(a[2], a[3]);
    return u.v;
}

// ---------------------------------------------------------------------------
// Fused projection GEMMs (proven R7): Out[M][320] = A[M][K]*W[320][K]^T + bias.
// ---------------------------------------------------------------------------
__global__ __launch_bounds__(512, 4)
void proj_fused(const float* __restrict__ enc_out, const float* __restrict__ enc_w,
                const float* __restrict__ enc_b, const float* __restrict__ pred_out,
                const float* __restrict__ pred_w, const float* __restrict__ pred_b,
                _Float16* __restrict__ F, _Float16* __restrict__ G) {
    __shared__ _Float16 As[2][64 * 40];
    __shared__ _Float16 Ws[2][64 * 40];

    int blk = blockIdx.x;
    const float *A, *W, *bias;
    _Float16* Out;
    int K, mt, nt;
    if (blk < 320) {
        A = enc_out; W = enc_w; bias = enc_b; Out = F; K = 768;
        mt = blk & 63; nt = blk >> 6;
    } else {
        blk -= 320;
        A = pred_out; W = pred_w; bias = pred_b; Out = G; K = 320;
        mt = blk & 15; nt = blk >> 4;
    }
    const int bm = mt * 64;
    const int bn = nt * 64;

    const int tid = threadIdx.x;
    const int l   = tid & 63;
    const int w   = tid >> 6;          // 0..7
    const int wm  = (w >> 2) * 32;     // 0,32
    const int wn  = (w & 3) * 16;      // 0,16,32,48
    const int q   = l >> 4;            // 0..3 (k-slice group)
    const int r16 = l & 15;

    const int srow = tid >> 3;         // 0..63
    const int scol = (tid & 7) * 4;    // float col 0,4,...,28

    f32x4 acc[2] = {};

    const float* arow = A + (size_t)(bm + srow) * K + scol;
    const float* wrow = W + (size_t)(bn + srow) * K + scol;

    // 2-deep prologue: K-steps 0 and 32 in flight
    f32x4 aA = *(const f32x4*)(arow);
    f32x4 wA = *(const f32x4*)(wrow);
    f32x4 aB = *(const f32x4*)(arow + 32);
    f32x4 wB = *(const f32x4*)(wrow + 32);

    for (int k0 = 0; k0 < K; k0 += 64) {
        // ---- phase A (buffer 0, K-step k0) ----
        *(f16x4*)&As[0][srow * 40 + scol] = pack4(aA);
        *(f16x4*)&Ws[0][srow * 40 + scol] = pack4(wA);
        if (k0 + 64 < K) {
            aA = *(const f32x4*)(arow + k0 + 64);
            wA = *(const f32x4*)(wrow + k0 + 64);
        }
        __syncthreads();
        {
            f16x8 af0 = *(const f16x8*)&As[0][(wm + r16) * 40 + q * 8];
            f16x8 af1 = *(const f16x8*)&As[0][(wm + 16 + r16) * 40 + q * 8];
            f16x8 bf  = *(const f16x8*)&Ws[0][(wn + r16) * 40 + q * 8];
            acc[0] = __builtin_amdgcn_mfma_f32_16x16x32_f16(af0, bf, acc[0], 0, 0, 0);
            acc[1] = __builtin_amdgcn_mfma_f32_16x16x32_f16(af1, bf, acc[1], 0, 0, 0);
        }
        // ---- phase B (buffer 1, K-step k0+32) ----
        *(f16x4*)&As[1][srow * 40 + scol] = pack4(aB);
        *(f16x4*)&Ws[1][srow * 40 + scol] = pack4(wB);
        if (k0 + 96 < K) {
            aB = *(const f32x4*)(arow + k0 + 96);
            wB = *(const f32x4*)(wrow + k0 + 96);
        }
        __syncthreads();
        {
            f16x8 af0 = *(const f16x8*)&As[1][(wm + r16) * 40 + q * 8];
            f16x8 af1 = *(const f16x8*)&As[1][(wm + 16 + r16) * 40 + q * 8];
            f16x8 bf  = *(const f16x8*)&Ws[1][(wn + r16) * 40 + q * 8];
            acc[0] = __builtin_amdgcn_mfma_f32_16x16x32_f16(af0, bf, acc[0], 0, 0, 0);
            acc[1] = __builtin_amdgcn_mfma_f32_16x16x32_f16(af1, bf, acc[1], 0, 0, 0);
        }
    }

    // Epilogue: C/D layout col = l&15 (n), row = (l>>4)*4 + rr (m)  [m89]
    {
        int col  = bn + wn + r16;
        float bv = bias[col];
#pragma unroll
        for (int mrep = 0; mrep < 2; ++mrep) {
#pragma unroll
            for (int rr = 0; rr < 4; ++rr) {
                int row = bm + wm + mrep * 16 + q * 4 + rr;
                Out[(size_t)row * H_ + col] = (_Float16)(acc[mrep][rr] + bv);
            }
        }
    }
}

// ---------------------------------------------------------------------------
// Joint kernel v16: R20 base structure at the proven-safe 2 blocks/CU, with
// t-unroll x4 (12 independent MFMA chains/wave, 2x R20's ILP). LDS = ow 34
// rows (21760) + flds (20480) + slabs (8704) = 50944 B but __launch_bounds__
// (256,2) PINS occupancy at 2 blocks/CU (the L2-capacity boundary: 3 blocks/CU
// refetches everything from HBM — R21). No overlay: acc needs 48 VGPRs, so
// bfr may sink into the loop (costs ~0.5us, proven R20 vs R17). NT full-line
// slab dumps. Waves barrier-free in the t-loop.
// ---------------------------------------------------------------------------
__global__ __launch_bounds__(256, 2)
void joint_kernel(const _Float16* __restrict__ F, const _Float16* __restrict__ G,
                  const float* __restrict__ out_w, const float* __restrict__ out_b,
                  float* __restrict__ out) {
    __shared__ _Float16 owlds[34 * 320];  // 21760 B; row stride 640 B, XOR-swizzled
    __shared__ _Float16 flds[32 * 320];   // 20480 B; linear
    __shared__ float    olds[4][544];     //  8704 B; per-wave 2176 B output slab

    const int tid = threadIdx.x;
    const int l   = tid & 63;
    const int w   = tid >> 6;
    const int q   = l >> 4;    // 0..3
    const int r16 = l & 15;
    const int tc  = blockIdx.x;  // 0..15 (t-chunk of 32)
    const int ut  = blockIdx.y;  // 0..7 (u-tile of 16)
    const int b   = blockIdx.z;  // 0..7
    const int u0  = ut * 16;

    char* ow = (char*)owlds;

    // stage out_w [34][320] fp32 -> fp16 swizzled LDS [34][320]
    for (int i = tid; i < 34 * 40; i += 256) {   // 1360 chunks of 8 f16
        int n  = i / 40;
        int c8 = (i - n * 40) * 8;               // f16 column
        f32x4 x0 = *(const f32x4*)(out_w + n * H_ + c8);
        f32x4 x1 = *(const f32x4*)(out_w + n * H_ + c8 + 4);
        *(f16x8*)(ow + n * 640 + ((c8 * 2) ^ ((n & 7) << 4))) = pack8(x0, x1);
    }

    // stage F chunk [32][320] f16 -> LDS, fully coalesced (1280 x 16B)
    {
        const _Float16* fsrc = F + ((size_t)b * T_ + tc * 32) * H_;
        for (int i = tid; i < 1280; i += 256)
            *(i32x4*)&flds[i * 8] = *(const i32x4*)(fsrc + i * 8);
    }

    // g fragments: per-lane row u0+r16, loop-invariant over t (A-operand m=u)
    f16x8 gfr[10];
    {
        const _Float16* grow = G + ((size_t)b * U_ + u0 + r16) * H_;
#pragma unroll
        for (int s = 0; s < 10; ++s)
            gfr[s] = *(const f16x8*)(grow + s * 32 + q * 8);
    }

    float ob[3];
#pragma unroll
    for (int nt = 0; nt < 3; ++nt) {
        int n = nt * 16 + r16;
        ob[nt] = (n < C_) ? out_b[n] : 0.f;
    }

    __syncthreads();

    // B-fragments (n=class) from swizzled LDS (conflict-free b128).
    // nt=2: only classes 32,33 exist -> r16<2 predicate.
    f16x8 bfr[3][10];
#pragma unroll
    for (int nt = 0; nt < 2; ++nt) {
        int n = nt * 16 + r16;
#pragma unroll
        for (int s = 0; s < 10; ++s)
            bfr[nt][s] = *(const f16x8*)(ow + n * 640 + ((s * 64 + q * 16) ^ ((n & 7) << 4)));
    }
#pragma unroll
    for (int s = 0; s < 10; ++s) {
        f16x8 v = {};
        if (r16 < 2) {
            int n = 32 + r16;
            v = *(const f16x8*)(ow + n * 640 + ((s * 64 + q * 16) ^ ((n & 7) << 4)));
        }
        bfr[2][s] = v;
    }

    float* slab = &olds[w][0];
    const f32x4* src = (const f32x4*)slab;
    const int tloc0 = w * 8;             // local t row within chunk

#pragma unroll
    for (int it = 0; it < 2; ++it) {
        const int tl0 = tloc0 + it * 4;
        const _Float16* fr0 = &flds[(tl0 + 0) * 320];
        const _Float16* fr1 = &flds[(tl0 + 1) * 320];
        const _Float16* fr2 = &flds[(tl0 + 2) * 320];
        const _Float16* fr3 = &flds[(tl0 + 3) * 320];

        f32x4 acc[4][3] = {};   // 12 independent chains (all indices static)
        __builtin_amdgcn_s_setprio(1);
#pragma unroll
        for (int s = 0; s < 10; ++s) {
            const f16x8 fz = {};
            f16x8 jv0 = __builtin_elementwise_max(*(const f16x8*)(fr0 + s * 32 + q * 8) + gfr[s], fz);
            f16x8 jv1 = __builtin_elementwise_max(*(const f16x8*)(fr1 + s * 32 + q * 8) + gfr[s], fz);
            f16x8 jv2 = __builtin_elementwise_max(*(const f16x8*)(fr2 + s * 32 + q * 8) + gfr[s], fz);
            f16x8 jv3 = __builtin_elementwise_max(*(const f16x8*)(fr3 + s * 32 + q * 8) + gfr[s], fz);
            acc[0][0] = __builtin_amdgcn_mfma_f32_16x16x32_f16(jv0, bfr[0][s], acc[0][0], 0, 0, 0);
            acc[1][0] = __builtin_amdgcn_mfma_f32_16x16x32_f16(jv1, bfr[0][s], acc[1][0], 0, 0, 0);
            acc[2][0] = __builtin_amdgcn_mfma_f32_16x16x32_f16(jv2, bfr[0][s], acc[2][0], 0, 0, 0);
            acc[3][0] = __builtin_amdgcn_mfma_f32_16x16x32_f16(jv3, bfr[0][s], acc[3][0], 0, 0, 0);
            acc[0][1] = __builtin_amdgcn_mfma_f32_16x16x32_f16(jv0, bfr[1][s], acc[0][1], 0, 0, 0);
            acc[1][1] = __builtin_amdgcn_mfma_f32_16x16x32_f16(jv1, bfr[1][s], acc[1][1], 0, 0, 0);
            acc[2][1] = __builtin_amdgcn_mfma_f32_16x16x32_f16(jv2, bfr[1][s], acc[2][1], 0, 0, 0);
            acc[3][1] = __builtin_amdgcn_mfma_f32_16x16x32_f16(jv3, bfr[1][s], acc[3][1], 0, 0, 0);
            acc[0][2] = __builtin_amdgcn_mfma_f32_16x16x32_f16(jv0, bfr[2][s], acc[0][2], 0, 0, 0);
            acc[1][2] = __builtin_amdgcn_mfma_f32_16x16x32_f16(jv1, bfr[2][s], acc[1][2], 0, 0, 0);
            acc[2][2] = __builtin_amdgcn_mfma_f32_16x16x32_f16(jv2, bfr[2][s], acc[2][2], 0, 0, 0);
            acc[3][2] = __builtin_amdgcn_mfma_f32_16x16x32_f16(jv3, bfr[2][s], acc[3][2], 0, 0, 0);
        }
        __builtin_amdgcn_s_setprio(0);

        // dump 4 t's sequentially through the wave-private slab
#pragma unroll
        for (int tt = 0; tt < 4; ++tt) {
            const int t = tc * 32 + tl0 + tt;
            float* obase = out + (((size_t)b * T_ + t) * U_ + u0) * C_;  // 64B-aligned
#pragma unroll
            for (int rr = 0; rr < 4; ++rr) {
                const int m = q * 4 + rr;
                slab[m * 34 + r16]      = acc[tt][0][rr] + ob[0];
                slab[m * 34 + 16 + r16] = acc[tt][1][rr] + ob[1];
                if (r16 < 2)
                    slab[m * 34 + 32 + r16] = acc[tt][2][rr] + ob[2];
            }
            {
                f32x4 v0 = src[l];
                f32x4 v1 = src[64 + l];
                __builtin_nontemporal_store(v0, (f32x4*)(obase + l * 4));
                __builtin_nontemporal_store(v1, (f32x4*)(obase + 256 + l * 4));
                if (l < 8) {
                    f32x4 v2 = src[128 + l];
                    __builtin_nontemporal_store(v2, (f32x4*)(obase + 512 + l * 4));
                }
            }
        }
    }
}

// ---------------------------------------------------------------------------
extern "C" void kernel_launch(void* const* d_in, const int* in_sizes, int n_in,
                              void* d_out, int out_size, void* d_ws, size_t ws_size,
                              hipStream_t stream) {
    const float* enc_out  = (const float*)d_in[0];
    const float* pred_out = (const float*)d_in[1];
    const float* enc_w    = (const float*)d_in[2];
    const float* enc_b    = (const float*)d_in[3];
    const float* pred_w   = (const float*)d_in[4];
    const float* pred_b   = (const float*)d_in[5];
    const float* out_w    = (const float*)d_in[6];
    const float* out_b    = (const float*)d_in[7];
    float* out = (float*)d_out;

    char* ws = (char*)d_ws;
    _Float16* F = (_Float16*)ws;                            // 4096*320 fp16
    _Float16* G = (_Float16*)(ws + (size_t)4096 * 320 * 2); // 1024*320 fp16

    proj_fused<<<400, 512, 0, stream>>>(enc_out, enc_w, enc_b,
                                        pred_out, pred_w, pred_b, F, G);
    joint_kernel<<<dim3(16, 8, 8), 256, 0, stream>>>(F, G, out_w, out_b, out);
}

// Round 23
// 41.685 us; speedup vs baseline: 2.6533x; 1.0208x over previous
//
#include <hip/hip_runtime.h>
#include <hip/hip_fp16.h>

// RNNT Joint: logits[b,t,u,c] = relu(f[b,t,:] + g[b,u,:]) . out_w[c,:] + out_b[c]
// f = enc_out @ enc_w^T + enc_b    [8,512,320]
// g = pred_out @ pred_w^T + pred_b [8,128,320]
// Sizes: B=8 T=512 U=128 E=768 P=320 H=320 C=34
// REVERT to R20 (best measured: 41.63 us).

typedef _Float16 f16x8 __attribute__((ext_vector_type(8)));
typedef _Float16 f16x4 __attribute__((ext_vector_type(4)));
typedef __fp16   fp16x2 __attribute__((ext_vector_type(2)));
typedef float    f32x4 __attribute__((ext_vector_type(4)));
typedef int      i32x4 __attribute__((ext_vector_type(4)));

#define B_ 8
#define T_ 512
#define U_ 128
#define H_ 320
#define C_ 34

__device__ inline f16x8 pack8(f32x4 a, f32x4 b) {
    union { fp16x2 h[4]; f16x8 v; } u;
    u.h[0] = __builtin_amdgcn_cvt_pkrtz(a[0], a[1]);
    u.h[1] = __builtin_amdgcn_cvt_pkrtz(a[2], a[3]);
    u.h[2] = __builtin_amdgcn_cvt_pkrtz(b[0], b[1]);
    u.h[3] = __builtin_amdgcn_cvt_pkrtz(b[2], b[3]);
    return u.v;
}

__device__ inline f16x4 pack4(f32x4 a) {
    union { fp16x2 h[2]; f16x4 v; } u;
    u.h[0] = __builtin_amdgcn_cvt_pkrtz(a[0], a[1]);
    u.h[1] = __builtin_amdgcn_cvt_pkrtz(a[2], a[3]);
    return u.v;
}

// ---------------------------------------------------------------------------
// Fused projection GEMMs (proven R7): Out[M][320] = A[M][K]*W[320][K]^T + bias.
// ---------------------------------------------------------------------------
__global__ __launch_bounds__(512, 4)
void proj_fused(const float* __restrict__ enc_out, const float* __restrict__ enc_w,
                const float* __restrict__ enc_b, const float* __restrict__ pred_out,
                const float* __restrict__ pred_w, const float* __restrict__ pred_b,
                _Float16* __restrict__ F, _Float16* __restrict__ G) {
    __shared__ _Float16 As[2][64 * 40];
    __shared__ _Float16 Ws[2][64 * 40];

    int blk = blockIdx.x;
    const float *A, *W, *bias;
    _Float16* Out;
    int K, mt, nt;
    if (blk < 320) {
        A = enc_out; W = enc_w; bias = enc_b; Out = F; K = 768;
        mt = blk & 63; nt = blk >> 6;
    } else {
        blk -= 320;
        A = pred_out; W = pred_w; bias = pred_b; Out = G; K = 320;
        mt = blk & 15; nt = blk >> 4;
    }
    const int bm = mt * 64;
    const int bn = nt * 64;

    const int tid = threadIdx.x;
    const int l   = tid & 63;
    const int w   = tid >> 6;          // 0..7
    const int wm  = (w >> 2) * 32;     // 0,32
    const int wn  = (w & 3) * 16;      // 0,16,32,48
    const int q   = l >> 4;            // 0..3 (k-slice group)
    const int r16 = l & 15;

    const int srow = tid >> 3;         // 0..63
    const int scol = (tid & 7) * 4;    // float col 0,4,...,28

    f32x4 acc[2] = {};

    const float* arow = A + (size_t)(bm + srow) * K + scol;
    const float* wrow = W + (size_t)(bn + srow) * K + scol;

    // 2-deep prologue: K-steps 0 and 32 in flight
    f32x4 aA = *(const f32x4*)(arow);
    f32x4 wA = *(const f32x4*)(wrow);
    f32x4 aB = *(const f32x4*)(arow + 32);
    f32x4 wB = *(const f32x4*)(wrow + 32);

    for (int k0 = 0; k0 < K; k0 += 64) {
        // ---- phase A (buffer 0, K-step k0) ----
        *(f16x4*)&As[0][srow * 40 + scol] = pack4(aA);
        *(f16x4*)&Ws[0][srow * 40 + scol] = pack4(wA);
        if (k0 + 64 < K) {
            aA = *(const f32x4*)(arow + k0 + 64);
            wA = *(const f32x4*)(wrow + k0 + 64);
        }
        __syncthreads();
        {
            f16x8 af0 = *(const f16x8*)&As[0][(wm + r16) * 40 + q * 8];
            f16x8 af1 = *(const f16x8*)&As[0][(wm + 16 + r16) * 40 + q * 8];
            f16x8 bf  = *(const f16x8*)&Ws[0][(wn + r16) * 40 + q * 8];
            acc[0] = __builtin_amdgcn_mfma_f32_16x16x32_f16(af0, bf, acc[0], 0, 0, 0);
            acc[1] = __builtin_amdgcn_mfma_f32_16x16x32_f16(af1, bf, acc[1], 0, 0, 0);
        }
        // ---- phase B (buffer 1, K-step k0+32) ----
        *(f16x4*)&As[1][srow * 40 + scol] = pack4(aB);
        *(f16x4*)&Ws[1][srow * 40 + scol] = pack4(wB);
        if (k0 + 96 < K) {
            aB = *(const f32x4*)(arow + k0 + 96);
            wB = *(const f32x4*)(wrow + k0 + 96);
        }
        __syncthreads();
        {
            f16x8 af0 = *(const f16x8*)&As[1][(wm + r16) * 40 + q * 8];
            f16x8 af1 = *(const f16x8*)&As[1][(wm + 16 + r16) * 40 + q * 8];
            f16x8 bf  = *(const f16x8*)&Ws[1][(wn + r16) * 40 + q * 8];
            acc[0] = __builtin_amdgcn_mfma_f32_16x16x32_f16(af0, bf, acc[0], 0, 0, 0);
            acc[1] = __builtin_amdgcn_mfma_f32_16x16x32_f16(af1, bf, acc[1], 0, 0, 0);
        }
    }

    // Epilogue: C/D layout col = l&15 (n), row = (l>>4)*4 + rr (m)  [m89]
    {
        int col  = bn + wn + r16;
        float bv = bias[col];
#pragma unroll
        for (int mrep = 0; mrep < 2; ++mrep) {
#pragma unroll
            for (int rr = 0; rr < 4; ++rr) {
                int row = bm + wm + mrep * 16 + q * 4 + rr;
                Out[(size_t)row * H_ + col] = (_Float16)(acc[mrep][rr] + bv);
            }
        }
    }
}

// ---------------------------------------------------------------------------
// Joint kernel v14 (R20, best): bfr register-resident via slab overlay at a
// fitting VGPR cap. __launch_bounds__(256,2) = 256-VGPR budget (bfr 120 +
// gfr 40 + acc 24 + temps ~= 200 fits, no spill). LDS: ow staging 30720 +
// flds 20480 = 51200 B; slabs overlaid on dead ow region; 2 blocks/CU
// (hard L2-capacity boundary — 3 blocks/CU refetches from HBM, R21).
// NT full-line slab dumps; x2-unrolled compute; setprio around MFMA cluster.
// ---------------------------------------------------------------------------
__global__ __launch_bounds__(256, 2)
void joint_kernel(const _Float16* __restrict__ F, const _Float16* __restrict__ G,
                  const float* __restrict__ out_w, const float* __restrict__ out_b,
                  float* __restrict__ out) {
    __shared__ _Float16 regA[48 * 320];   // 30720 B: ow staging, then output slabs
    __shared__ _Float16 flds[32 * 320];   // 20480 B: F chunk

    const int tid = threadIdx.x;
    const int l   = tid & 63;
    const int w   = tid >> 6;
    const int q   = l >> 4;    // 0..3
    const int r16 = l & 15;
    const int tc  = blockIdx.x;  // 0..15 (t-chunk of 32)
    const int ut  = blockIdx.y;  // 0..7 (u-tile of 16)
    const int b   = blockIdx.z;  // 0..7
    const int u0  = ut * 16;

    char* ow = (char*)regA;

    // stage out_w [34][320] fp32 -> fp16 swizzled LDS [48][320] (rows 34..47 = 0)
    for (int i = tid; i < 48 * 40; i += 256) {   // 1920 chunks of 8 f16
        int n  = i / 40;
        int c8 = (i - n * 40) * 8;               // f16 column
        f16x8 v = {};
        if (n < C_) {
            f32x4 x0 = *(const f32x4*)(out_w + n * H_ + c8);
            f32x4 x1 = *(const f32x4*)(out_w + n * H_ + c8 + 4);
            v = pack8(x0, x1);
        }
        *(f16x8*)(ow + n * 640 + ((c8 * 2) ^ ((n & 7) << 4))) = v;
    }

    // stage F chunk [32][320] f16 -> LDS, fully coalesced (1280 x 16B)
    {
        const _Float16* fsrc = F + ((size_t)b * T_ + tc * 32) * H_;
        for (int i = tid; i < 1280; i += 256)
            *(i32x4*)&flds[i * 8] = *(const i32x4*)(fsrc + i * 8);
    }

    // g fragments: per-lane row u0+r16, loop-invariant over t (A-operand m=u)
    f16x8 gfr[10];
    {
        const _Float16* grow = G + ((size_t)b * U_ + u0 + r16) * H_;
#pragma unroll
        for (int s = 0; s < 10; ++s)
            gfr[s] = *(const f16x8*)(grow + s * 32 + q * 8);
    }

    float ob[3];
#pragma unroll
    for (int nt = 0; nt < 3; ++nt) {
        int n = nt * 16 + r16;
        ob[nt] = (n < C_) ? out_b[n] : 0.f;
    }

    __syncthreads();  // ow staging complete

    // B-fragments (n=class) from swizzled LDS (conflict-free b128)
    f16x8 bfr[3][10];
#pragma unroll
    for (int nt = 0; nt < 3; ++nt) {
        int n = nt * 16 + r16;
#pragma unroll
        for (int s = 0; s < 10; ++s)
            bfr[nt][s] = *(const f16x8*)(ow + n * 640 + ((s * 64 + q * 16) ^ ((n & 7) << 4)));
    }

    __syncthreads();  // all waves done reading ow -> regA becomes the slabs

    float* slab = (float*)regA + w * 544;   // per-wave 2176 B slab (overlay)
    const f32x4* src = (const f32x4*)slab;
    const int tloc0 = w * 8;                // local t row within chunk

#pragma unroll
    for (int it = 0; it < 4; ++it) {
        const int tl0 = tloc0 + it * 2;
        const _Float16* fr0 = &flds[tl0 * 320];
        const _Float16* fr1 = &flds[(tl0 + 1) * 320];

        f32x4 a00 = {}, a01 = {}, a02 = {};
        f32x4 a10 = {}, a11 = {}, a12 = {};
        __builtin_amdgcn_s_setprio(1);
#pragma unroll
        for (int s = 0; s < 10; ++s) {
            const f16x8 fz = {};
            f16x8 fv0 = *(const f16x8*)(fr0 + s * 32 + q * 8);
            f16x8 fv1 = *(const f16x8*)(fr1 + s * 32 + q * 8);
            f16x8 jv0 = __builtin_elementwise_max(fv0 + gfr[s], fz);
            f16x8 jv1 = __builtin_elementwise_max(fv1 + gfr[s], fz);
            a00 = __builtin_amdgcn_mfma_f32_16x16x32_f16(jv0, bfr[0][s], a00, 0, 0, 0);
            a10 = __builtin_amdgcn_mfma_f32_16x16x32_f16(jv1, bfr[0][s], a10, 0, 0, 0);
            a01 = __builtin_amdgcn_mfma_f32_16x16x32_f16(jv0, bfr[1][s], a01, 0, 0, 0);
            a11 = __builtin_amdgcn_mfma_f32_16x16x32_f16(jv1, bfr[1][s], a11, 0, 0, 0);
            a02 = __builtin_amdgcn_mfma_f32_16x16x32_f16(jv0, bfr[2][s], a02, 0, 0, 0);
            a12 = __builtin_amdgcn_mfma_f32_16x16x32_f16(jv1, bfr[2][s], a12, 0, 0, 0);
        }
        __builtin_amdgcn_s_setprio(0);

        const int t0 = tc * 32 + tl0;
        float* ob0 = out + (((size_t)b * T_ + t0) * U_ + u0) * C_;  // 64B-aligned
        float* ob1 = ob0 + (size_t)U_ * C_;

        // ---- t0: scatter slab, dump NT full-line ----
#pragma unroll
        for (int rr = 0; rr < 4; ++rr) {
            const int m = q * 4 + rr;
            slab[m * 34 + r16]      = a00[rr] + ob[0];
            slab[m * 34 + 16 + r16] = a01[rr] + ob[1];
            if (r16 < 2)
                slab[m * 34 + 32 + r16] = a02[rr] + ob[2];
        }
        {
            f32x4 v0 = src[l];
            f32x4 v1 = src[64 + l];
            __builtin_nontemporal_store(v0, (f32x4*)(ob0 + l * 4));
            __builtin_nontemporal_store(v1, (f32x4*)(ob0 + 256 + l * 4));
            if (l < 8) {
                f32x4 v2 = src[128 + l];
                __builtin_nontemporal_store(v2, (f32x4*)(ob0 + 512 + l * 4));
            }
        }

        // ---- t1: reuse slab (same-wave LDS ops retire in order), dump NT ----
#pragma unroll
        for (int rr = 0; rr < 4; ++rr) {
            const int m = q * 4 + rr;
            slab[m * 34 + r16]      = a10[rr] + ob[0];
            slab[m * 34 + 16 + r16] = a11[rr] + ob[1];
            if (r16 < 2)
                slab[m * 34 + 32 + r16] = a12[rr] + ob[2];
        }
        {
            f32x4 v0 = src[l];
            f32x4 v1 = src[64 + l];
            __builtin_nontemporal_store(v0, (f32x4*)(ob1 + l * 4));
            __builtin_nontemporal_store(v1, (f32x4*)(ob1 + 256 + l * 4));
            if (l < 8) {
                f32x4 v2 = src[128 + l];
                __builtin_nontemporal_store(v2, (f32x4*)(ob1 + 512 + l * 4));
            }
        }
    }
}

// ---------------------------------------------------------------------------
extern "C" void kernel_launch(void* const* d_in, const int* in_sizes, int n_in,
                              void* d_out, int out_size, void* d_ws, size_t ws_size,
                              hipStream_t stream) {
    const float* enc_out  = (const float*)d_in[0];
    const float* pred_out = (const float*)d_in[1];
    const float* enc_w    = (const float*)d_in[2];
    const float* enc_b    = (const float*)d_in[3];
    const float* pred_w   = (const float*)d_in[4];
    const float* pred_b   = (const float*)d_in[5];
    const float* out_w    = (const float*)d_in[6];
    const float* out_b    = (const float*)d_in[7];
    float* out = (float*)d_out;

    char* ws = (char*)d_ws;
    _Float16* F = (_Float16*)ws;                            // 4096*320 fp16
    _Float16* G = (_Float16*)(ws + (size_t)4096 * 320 * 2); // 1024*320 fp16

    proj_fused<<<400, 512, 0, stream>>>(enc_out, enc_w, enc_b,
                                        pred_out, pred_w, pred_b, F, G);
    joint_kernel<<<dim3(16, 8, 8), 256, 0, stream>>>(F, G, out_w, out_b, out);
}